// Round 3
// baseline (225.586 us; speedup 1.0000x reference)
//
#include <hip/hip_runtime.h>
#include <hip/hip_bf16.h>

#define N_EDGES 1000000
#define N_TILES (N_EDGES / 16)
#define N_NODES 100000
#define CONV_BLOCKS ((N_NODES * 64 / 8) / 256)   // 3125, exact

typedef __attribute__((ext_vector_type(8))) short short8;
typedef __attribute__((ext_vector_type(4))) int intx4;
typedef __attribute__((ext_vector_type(4))) float floatx4;
typedef __attribute__((ext_vector_type(2))) float floatx2;

// LDS layout (bytes) inside edgehead block:
//   [0, 16896)      Wt B-fragments, fragment-major, stride 33 chunks
//   [16896, 17920)  wsel per lane (64 x 16 B)
//   [17920, 18432)  per-c epilogue constants: {Gn0,Gn1,Bn0,Bn1,W20,W21,pad,pad} x 16
#define WSEL_BASE 16896
#define GBW_BASE  17920
#define LDS_BYTES 18432   // x8 blocks/CU = 147,456 B < 160 KiB -> 8 blocks/CU OK

__device__ __forceinline__ short f2bf(float f) {
    __bf16 b = (__bf16)f;           // RNE convert, native on gfx950
    return __builtin_bit_cast(short, b);
}

union BI { short8 s8; intx4 i4; __hip_bfloat162 b2[4]; };

// |a-b| in bf16 (packed): 4x v_pk sub + 4x dword AND
__device__ __forceinline__ short8 dabs8(short8 a, short8 b) {
    BI ua, ub, ud;
    ua.s8 = a; ub.s8 = b;
#pragma unroll
    for (int i = 0; i < 4; ++i) ud.b2[i] = __hsub2(ua.b2[i], ub.b2[i]);
    ud.i4 &= 0x7fff7fff;            // bf16 abs, packed per-dword
    return ud.s8;
}
// a*b in bf16 (packed)
__device__ __forceinline__ short8 pmul8(short8 a, short8 b) {
    BI ua, ub, up;
    ua.s8 = a; ub.s8 = b;
#pragma unroll
    for (int i = 0; i < 4; ++i) up.b2[i] = __hmul2(ua.b2[i], ub.b2[i]);
    return up.s8;
}

// ---- fused prep: blocks [0, 3125) = h fp32->bf16; blocks [3125, 3157) = W prep.
__global__ __launch_bounds__(256) void prep_kernel(
    const float* __restrict__ h, unsigned short* __restrict__ hb,
    const float* __restrict__ gamma, const float* __restrict__ beta,
    const float* __restrict__ W1, unsigned short* __restrict__ Wt,
    float* __restrict__ GB)
{
    if (blockIdx.x < CONV_BLOCKS) {
        const int i = blockIdx.x * blockDim.x + threadIdx.x;   // < 800000 exactly
        const float* p = h + (long)i * 8;
        floatx4 a = *(const floatx4*)p;
        floatx4 b = *(const floatx4*)(p + 4);
        short8 o;
        o[0] = f2bf(a[0]); o[1] = f2bf(a[1]); o[2] = f2bf(a[2]); o[3] = f2bf(a[3]);
        o[4] = f2bf(b[0]); o[5] = f2bf(b[1]); o[6] = f2bf(b[2]); o[7] = f2bf(b[3]);
        *(short8*)(hb + (long)i * 8) = o;
        return;
    }
    // ---- W prep: one block per output n (32 blocks x 256 threads)
    const int n = blockIdx.x - CONV_BLOCKS;
    const int k = threadIdx.x;
    const float w1 = W1[k * 32 + n];
    float G = gamma[k] * w1;
    float B = beta[k] * w1;
    Wt[n * 256 + k] = (unsigned short)f2bf(G);
    G += __shfl_xor(G, 1);  B += __shfl_xor(B, 1);
    G += __shfl_xor(G, 2);  B += __shfl_xor(B, 2);
    G += __shfl_xor(G, 4);  B += __shfl_xor(B, 4);
    G += __shfl_xor(G, 8);  B += __shfl_xor(B, 8);
    G += __shfl_xor(G, 16); B += __shfl_xor(B, 16);
    G += __shfl_xor(G, 32); B += __shfl_xor(B, 32);
    __shared__ float sG[4], sB[4];
    if ((k & 63) == 0) { sG[k >> 6] = G; sB[k >> 6] = B; }
    __syncthreads();
    if (k == 0) {
        GB[n]      = sG[0] + sG[1] + sG[2] + sG[3];
        GB[32 + n] = sB[0] + sB[1] + sB[2] + sB[3];
    }
}

// ---- main: R10 configuration.
// R9 ping-pong body, but loop-invariant per-lane constants (wsel, LN/W2
// epilogue scalars) moved to LDS and re-read per tile (addresses ride the
// anti-LICM asm barrier). __launch_bounds__(256,8) pins unified VGPR <= 64
// -> 8 waves/SIMD. Empirical law from R7/R8/R9: time and FETCH both track
// resident waves; 64 VGPR is the boundary (HW granule ~16 rounds 72->80).
__global__ __launch_bounds__(256, 8) void edgehead_kernel(
    const unsigned short* __restrict__ hb,
    const int* __restrict__ ep,
    const float* __restrict__ b1,
    const float* __restrict__ W2,
    const float* __restrict__ b2p,
    const unsigned short* __restrict__ Wt,
    const float* __restrict__ GB,
    float* __restrict__ out)
{
    const int lane = threadIdx.x & 63;
    const int c = lane & 15;   // A-row index; D column
    const int q = lane >> 4;   // quad
    const int wid = (int)((blockIdx.x * blockDim.x + threadIdx.x) >> 6);
    const int nw = (int)((gridDim.x * blockDim.x) >> 6);

    __shared__ __align__(16) char lds_all[LDS_BYTES];
    short* lds_wt = (short*)lds_all;

    // Stage Wt, fragment-major: row r = n (0..31), chunk j = 4s+q (0..31).
    for (int idx = threadIdx.x; idx < 1024; idx += 256) {
        const int r = idx >> 5, j = idx & 31;
        *(short8*)(lds_wt + (r * 33 + j) * 8) = *(const short8*)(Wt + r * 256 + 8 * j);
    }
    // Stage wsel: selector B for the final dot, per lane (same for all waves):
    // B[8q+j][c] = (c == 4q+(j&3)) ? 1 : 0
    if (threadIdx.x < 64) {
        const int cc = threadIdx.x & 15, qq = threadIdx.x >> 4;
        short8 w;
#pragma unroll
        for (int j = 0; j < 8; ++j) w[j] = (cc == 4 * qq + (j & 3)) ? (short)0x3F80 : (short)0;
        *(short8*)(lds_all + WSEL_BASE + threadIdx.x * 16) = w;
    }
    // Stage per-c epilogue constants
    if (threadIdx.x < 16) {
        const int cc = threadIdx.x;
        float* g = (float*)(lds_all + GBW_BASE + cc * 32);
        g[0] = GB[cc];
        g[1] = GB[16 + cc];
        g[2] = GB[32 + cc] + b1[cc];
        g[3] = GB[48 + cc] + b1[16 + cc];
        g[4] = W2[cc];
        g[5] = W2[16 + cc];
    }
    __syncthreads();

    short8 ones;
#pragma unroll
    for (int j = 0; j < 8; ++j) ones[j] = (short)0x3F80;   // bf16 1.0

    const float b2 = b2p[0];

    int t = wid;
    if (t >= N_TILES) return;

    // per-lane LDS offsets; clobbered by the asm barrier each tile so the
    // constants are re-read from LDS (keeps them out of long-lived VGPRs)
    int wt_off = (c * 33 + q) * 8;          // shorts; nt=1 adds 16*33*8
    int ws_off = WSEL_BASE + lane * 16;     // bytes
    int gb_off = GBW_BASE + c * 32;         // bytes

#define IDX_LOAD(tt, S, D) { int _t = (tt); if (_t >= N_TILES) _t = wid;          \
                             const int _e = _t * 16 + c;                          \
                             S = ep[_e]; D = ep[N_EDGES + _e]; }
#define ROW_ISSUE(S, D, U0, U1, V0, V1)                                           \
    U0 = *(const short8*)(hb + (long)(S) * 64 + 8 * q);                           \
    U1 = *(const short8*)(hb + (long)(S) * 64 + 8 * q + 32);                      \
    V0 = *(const short8*)(hb + (long)(D) * 64 + 8 * q);                           \
    V1 = *(const short8*)(hb + (long)(D) * 64 + 8 * q + 32);

    short8 aU0, aU1, aV0, aV1;   // slot A (even bodies)
    short8 bU0, bU1, bV0, bV1;   // slot B (odd bodies)
    int sA, dA, sB, dB;

    // ---- prologue: rows(t) into A; idx(t+nw) in B-regs; idx(t+2nw) in A-regs
    IDX_LOAD(t, sA, dA);
    ROW_ISSUE(sA, dA, aU0, aU1, aV0, aV1);
    IDX_LOAD(t + nw,     sB, dB);
    IDX_LOAD(t + 2 * nw, sA, dA);

#define BODY(U0, U1, V0, V1, NU0, NU1, NV0, NV1, SN, DN)                          \
  {                                                                               \
    if (t >= N_TILES) goto tail;                                                  \
    asm("" : "+v"(wt_off), "+v"(ws_off), "+v"(gb_off));  /* defeat LICM */        \
    ROW_ISSUE(SN, DN, NU0, NU1, NV0, NV1);                                        \
    IDX_LOAD(t + 3 * nw, SN, DN);                                                 \
    /* per-tile LDS constant reads (issued early, consumed in epilogue) */        \
    const floatx4 gbv = *(const floatx4*)(lds_all + gb_off);                      \
    const floatx2 w2v = *(const floatx2*)(lds_all + gb_off + 16);                 \
    const short8 wsel = *(const short8*)(lds_all + ws_off);                       \
    floatx4 acc0 = {0.f, 0.f, 0.f, 0.f};                                          \
    floatx4 acc1 = {0.f, 0.f, 0.f, 0.f};                                          \
    floatx4 asum = {0.f, 0.f, 0.f, 0.f};   /* row sums */                         \
    floatx4 agrm = {0.f, 0.f, 0.f, 0.f};   /* Gram; diag = sum of squares */      \
    _Pragma("unroll")                                                             \
    for (int s = 0; s < 8; ++s) {                                                 \
      short8 af;                                                                  \
      switch (s) {                                                                \
        case 0: af = U0; break;                                                   \
        case 1: af = U1; break;                                                   \
        case 2: af = V0; break;                                                   \
        case 3: af = V1; break;                                                   \
        case 4: af = dabs8(U0, V0); break;    /* lazy: short live ranges */       \
        case 5: af = dabs8(U1, V1); break;                                        \
        case 6: af = pmul8(U0, V0); break;                                        \
        default: af = pmul8(U1, V1); break;                                       \
      }                                                                           \
      const short8 bf0 = *(const short8*)(lds_wt + wt_off + s * 32);              \
      const short8 bf1 = *(const short8*)(lds_wt + wt_off + 16 * 33 * 8 + s * 32);\
      acc0 = __builtin_amdgcn_mfma_f32_16x16x32_bf16(af, bf0,  acc0, 0, 0, 0);    \
      acc1 = __builtin_amdgcn_mfma_f32_16x16x32_bf16(af, bf1,  acc1, 0, 0, 0);    \
      asum = __builtin_amdgcn_mfma_f32_16x16x32_bf16(af, ones, asum, 0, 0, 0);    \
      agrm = __builtin_amdgcn_mfma_f32_16x16x32_bf16(af, af,   agrm, 0, 0, 0);    \
    }                                                                             \
    float ss[4];                                                                  \
    _Pragma("unroll")                                                             \
    for (int r = 0; r < 4; ++r) ss[r] = __shfl(agrm[r], 20 * q + r);              \
    short8 af2;                                                                   \
    _Pragma("unroll")                                                             \
    for (int r = 0; r < 4; ++r) {                                                 \
      const float mu  = asum[r] * (1.f / 256.f);                                  \
      const float var = fmaf(ss[r], 1.f / 256.f, -mu * mu);                       \
      const float rs  = rsqrtf(var + 1e-5f);                                      \
      float h0 = fmaf(rs, fmaf(-mu, gbv[0], acc0[r]), gbv[2]); h0 = fmaxf(h0, 0.f);\
      float h1 = fmaf(rs, fmaf(-mu, gbv[1], acc1[r]), gbv[3]); h1 = fmaxf(h1, 0.f);\
      af2[r]     = f2bf(h0 * w2v[0]);                                             \
      af2[4 + r] = f2bf(h1 * w2v[1]);                                             \
    }                                                                             \
    floatx4 dfin = {0.f, 0.f, 0.f, 0.f};                                          \
    dfin = __builtin_amdgcn_mfma_f32_16x16x32_bf16(af2, wsel, dfin, 0, 0, 0);     \
    float part = (dfin[0] + dfin[1]) + (dfin[2] + dfin[3]);                       \
    part += __shfl_xor(part, 16);                                                 \
    part += __shfl_xor(part, 32);                                                 \
    if (q == 0) out[t * 16 + c] = part + b2;   /* coalesced 64B store */          \
    t += nw;                                                                      \
  }

    for (;;) {
        // even body: compute A(t), issue B rows (t+nw), refill B idx (t+3nw)
        BODY(aU0, aU1, aV0, aV1, bU0, bU1, bV0, bV1, sB, dB);
        // odd body: compute B, issue A, refill A idx
        BODY(bU0, bU1, bV0, bV1, aU0, aU1, aV0, aV1, sA, dA);
    }
tail:
    return;
#undef BODY
#undef ROW_ISSUE
#undef IDX_LOAD
}

extern "C" void kernel_launch(void* const* d_in, const int* in_sizes, int n_in,
                              void* d_out, int out_size, void* d_ws, size_t ws_size,
                              hipStream_t stream) {
    const float* h     = (const float*)d_in[0];
    const int*   ep    = (const int*)d_in[1];
    const float* gamma = (const float*)d_in[2];
    const float* beta  = (const float*)d_in[3];
    const float* W1    = (const float*)d_in[4];
    const float* b1    = (const float*)d_in[5];
    const float* W2    = (const float*)d_in[6];
    const float* b2    = (const float*)d_in[7];
    float* out = (float*)d_out;

    unsigned short* hb = (unsigned short*)d_ws;                      // 12,800,000 B
    unsigned short* Wt = (unsigned short*)((char*)d_ws + 12800000);  // 16,384 B
    float* GB = (float*)((char*)d_ws + 12800000 + 16384);            // 64 floats

    prep_kernel<<<CONV_BLOCKS + 32, 256, 0, stream>>>(h, hb, gamma, beta, W1, Wt, GB);
    edgehead_kernel<<<2048, 256, 0, stream>>>(hb, ep, b1, W2, b2, Wt, GB, out);
}

// Round 4
// 130.189 us; speedup vs baseline: 1.7328x; 1.7328x over previous
//
#include <hip/hip_runtime.h>
#include <hip/hip_bf16.h>

#define N_EDGES 1000000
#define N_TILES (N_EDGES / 16)
#define N_NODES 100000
#define CONV_BLOCKS ((N_NODES * 64 / 8) / 256)   // 3125, exact

typedef __attribute__((ext_vector_type(8))) short short8;
typedef __attribute__((ext_vector_type(4))) float floatx4;

__device__ __forceinline__ short f2bf(float f) {
    __bf16 b = (__bf16)f;           // RNE convert, native on gfx950
    return __builtin_bit_cast(short, b);
}

// |a-b| and a*b elementwise in bf16 (no f32 round-trip; same RNE results)
union BU { short8 s8; __hip_bfloat162 b2[4]; };
__device__ __forceinline__ void dp8(short8 a, short8 b, short8& d, short8& p) {
    BU ua, ub, ud, up;
    ua.s8 = a; ub.s8 = b;
#pragma unroll
    for (int i = 0; i < 4; ++i) {
        ud.b2[i] = __hsub2(ua.b2[i], ub.b2[i]);
        up.b2[i] = __hmul2(ua.b2[i], ub.b2[i]);
    }
#pragma unroll
    for (int j = 0; j < 8; ++j) ud.s8[j] = (short)(ud.s8[j] & 0x7fff);  // bf16 abs
    d = ud.s8; p = up.s8;
}

// ---- fused prep: blocks [0, 3125) = h fp32->bf16; blocks [3125, 3157) = W prep.
// Fusion validated R9-vs-R7: saves ~5 us of launch/gap time.
__global__ __launch_bounds__(256) void prep_kernel(
    const float* __restrict__ h, unsigned short* __restrict__ hb,
    const float* __restrict__ gamma, const float* __restrict__ beta,
    const float* __restrict__ W1, unsigned short* __restrict__ Wt,
    float* __restrict__ GB)
{
    if (blockIdx.x < CONV_BLOCKS) {
        const int i = blockIdx.x * blockDim.x + threadIdx.x;   // < 800000 exactly
        const float* p = h + (long)i * 8;
        floatx4 a = *(const floatx4*)p;
        floatx4 b = *(const floatx4*)(p + 4);
        short8 o;
        o[0] = f2bf(a[0]); o[1] = f2bf(a[1]); o[2] = f2bf(a[2]); o[3] = f2bf(a[3]);
        o[4] = f2bf(b[0]); o[5] = f2bf(b[1]); o[6] = f2bf(b[2]); o[7] = f2bf(b[3]);
        *(short8*)(hb + (long)i * 8) = o;
        return;
    }
    // ---- W prep: one block per output n (32 blocks x 256 threads)
    const int n = blockIdx.x - CONV_BLOCKS;
    const int k = threadIdx.x;
    const float w1 = W1[k * 32 + n];
    float G = gamma[k] * w1;
    float B = beta[k] * w1;
    Wt[n * 256 + k] = (unsigned short)f2bf(G);
    G += __shfl_xor(G, 1);  B += __shfl_xor(B, 1);
    G += __shfl_xor(G, 2);  B += __shfl_xor(B, 2);
    G += __shfl_xor(G, 4);  B += __shfl_xor(B, 4);
    G += __shfl_xor(G, 8);  B += __shfl_xor(B, 8);
    G += __shfl_xor(G, 16); B += __shfl_xor(B, 16);
    G += __shfl_xor(G, 32); B += __shfl_xor(B, 32);
    __shared__ float sG[4], sB[4];
    if ((k & 63) == 0) { sG[k >> 6] = G; sB[k >> 6] = B; }
    __syncthreads();
    if (k == 0) {
        GB[n]      = sG[0] + sG[1] + sG[2] + sG[3];
        GB[32 + n] = sB[0] + sB[1] + sB[2] + sB[3];
    }
}

// ---- main: R11 = exact R7 body (proven 52 us, 56 VGPR, 8 waves/SIMD).
// R8 (3-slot, 84 VGPR), R9 (ping-pong, 72 VGPR), R10 (launch_bounds pin,
// 32 VGPR + scratch spills) all lost waves or spilled: throughput here
// tracks resident waves, and this body is the known 64-VGPR-class optimum.
// 16 edges/wave; MFMA computes MLP, LN stats (ones-B + Gram diag), and the
// final W2 dot (selector-B). B-fragments live in LDS (fragment-major, stride
// 33 chunks). Gather is the bound: FETCH ~93 MB = hb x 8 XCDs (structural).
__global__ __launch_bounds__(256) void edgehead_kernel(
    const unsigned short* __restrict__ hb,
    const int* __restrict__ ep,
    const float* __restrict__ b1,
    const float* __restrict__ W2,
    const float* __restrict__ b2p,
    const unsigned short* __restrict__ Wt,
    const float* __restrict__ GB,
    float* __restrict__ out)
{
    const int lane = threadIdx.x & 63;
    const int c = lane & 15;   // A-row index; D column
    const int q = lane >> 4;   // quad
    const int wid = (int)((blockIdx.x * blockDim.x + threadIdx.x) >> 6);
    const int nw = (int)((gridDim.x * blockDim.x) >> 6);

    // Stage Wt into LDS, fragment-major: row r = n (0..31), chunk j = 4s+q (0..31).
    __shared__ short lds_wt[32 * 33 * 8];   // 16,896 B
    for (int idx = threadIdx.x; idx < 1024; idx += 256) {
        const int r = idx >> 5, j = idx & 31;
        *(short8*)(lds_wt + (r * 33 + j) * 8) = *(const short8*)(Wt + r * 256 + 8 * j);
    }
    __syncthreads();

    // per-lane base offset (in shorts) for its fragments: row c / row 16+c, chunk q
    int wt_off = (c * 33 + q) * 8;          // nt=0; nt=1 adds 16*33*8
    short8 ones;
#pragma unroll
    for (int j = 0; j < 8; ++j) ones[j] = (short)0x3F80;   // bf16 1.0

    // selector B for the final dot: B[8q+j][c] = (c == 4q+(j&3)) ? 1 : 0
    short8 wsel;
#pragma unroll
    for (int j = 0; j < 8; ++j) wsel[j] = (c == 4 * q + (j & 3)) ? (short)0x3F80 : (short)0;

    const float Gn0 = GB[c],      Gn1 = GB[16 + c];
    const float Bn0 = GB[32 + c] + b1[c];
    const float Bn1 = GB[48 + c] + b1[16 + c];
    const float W20 = W2[c],      W21 = W2[16 + c];
    const float b2  = b2p[0];

    int t = wid;
    if (t >= N_TILES) return;

    // --- prologue: rows(t), idx(t+nw)
    int s0 = ep[t * 16 + c];
    int d0 = ep[N_EDGES + t * 16 + c];
    short8 au0 = *(const short8*)(hb + (long)s0 * 64 + 8 * q);
    short8 au1 = *(const short8*)(hb + (long)s0 * 64 + 8 * q + 32);
    short8 av0 = *(const short8*)(hb + (long)d0 * 64 + 8 * q);
    short8 av1 = *(const short8*)(hb + (long)d0 * 64 + 8 * q + 32);
    int t1 = t + nw;
    int e1 = (t1 < N_TILES ? t1 : t) * 16 + c;
    int s1i = ep[e1];
    int d1i = ep[N_EDGES + e1];

    for (; t < N_TILES; t += nw) {
        // defeat LICM: compiler must re-read B-fragments from LDS each iter
        asm("" : "+v"(wt_off));

        // issue next tile's row loads (latency overlapped with compute below)
        short8 nu0 = *(const short8*)(hb + (long)s1i * 64 + 8 * q);
        short8 nu1 = *(const short8*)(hb + (long)s1i * 64 + 8 * q + 32);
        short8 nv0 = *(const short8*)(hb + (long)d1i * 64 + 8 * q);
        short8 nv1 = *(const short8*)(hb + (long)d1i * 64 + 8 * q + 32);
        // prefetch idx(t+2nw)
        {
            const int tn = t + 2 * nw;
            const int en = (tn < N_TILES ? tn : t) * 16 + c;
            s1i = ep[en];
            d1i = ep[N_EDGES + en];
        }

        // feat build fully in bf16 (packed)
        short8 ad0, ad1, ap0, ap1;
        dp8(au0, av0, ad0, ap0);
        dp8(au1, av1, ad1, ap1);

        floatx4 acc0 = {0.f, 0.f, 0.f, 0.f};
        floatx4 acc1 = {0.f, 0.f, 0.f, 0.f};
        floatx4 asum = {0.f, 0.f, 0.f, 0.f};   // row sums (same in every column lane)
        floatx4 agrm = {0.f, 0.f, 0.f, 0.f};   // Gram; diagonal = sum of squares
#pragma unroll
        for (int s = 0; s < 8; ++s) {
            short8 af;
            switch (s) {
                case 0: af = au0; break;
                case 1: af = au1; break;
                case 2: af = av0; break;
                case 3: af = av1; break;
                case 4: af = ad0; break;
                case 5: af = ad1; break;
                case 6: af = ap0; break;
                default: af = ap1; break;
            }
            const short8 bf0 = *(const short8*)(lds_wt + wt_off + s * 32);
            const short8 bf1 = *(const short8*)(lds_wt + wt_off + 16 * 33 * 8 + s * 32);
            acc0 = __builtin_amdgcn_mfma_f32_16x16x32_bf16(af, bf0,  acc0, 0, 0, 0);
            acc1 = __builtin_amdgcn_mfma_f32_16x16x32_bf16(af, bf1,  acc1, 0, 0, 0);
            asum = __builtin_amdgcn_mfma_f32_16x16x32_bf16(af, ones, asum, 0, 0, 0);
            agrm = __builtin_amdgcn_mfma_f32_16x16x32_bf16(af, af,   agrm, 0, 0, 0);
        }

        // LN epilogue + hmid*W2 packed as A-fragment for the selector MFMA.
        // acc0[r] = pre-LN hmid[edge=4q+r][n=c]; acc1[r] = [n=16+c].
        float ss[4];
#pragma unroll
        for (int r = 0; r < 4; ++r) ss[r] = __shfl(agrm[r], 20 * q + r);
        short8 af2;
#pragma unroll
        for (int r = 0; r < 4; ++r) {
            const float mu  = asum[r] * (1.f / 256.f);
            const float var = fmaf(ss[r], 1.f / 256.f, -mu * mu);
            const float rs  = rsqrtf(var + 1e-5f);
            float h0 = fmaf(rs, fmaf(-mu, Gn0, acc0[r]), Bn0); h0 = fmaxf(h0, 0.f);
            float h1 = fmaf(rs, fmaf(-mu, Gn1, acc1[r]), Bn1); h1 = fmaxf(h1, 0.f);
            af2[r]     = f2bf(h0 * W20);
            af2[4 + r] = f2bf(h1 * W21);
        }
        floatx4 dfin = {0.f, 0.f, 0.f, 0.f};
        dfin = __builtin_amdgcn_mfma_f32_16x16x32_bf16(af2, wsel, dfin, 0, 0, 0);
        // lane (c,q) reg r = hmidW2[c][4q+r] + hmidW2[c][4q+r+16]
        float part = (dfin[0] + dfin[1]) + (dfin[2] + dfin[3]);
        part += __shfl_xor(part, 16);
        part += __shfl_xor(part, 32);
        if (q == 0) out[t * 16 + c] = part + b2;   // coalesced 64B store

        au0 = nu0; au1 = nu1; av0 = nv0; av1 = nv1;
    }
}

extern "C" void kernel_launch(void* const* d_in, const int* in_sizes, int n_in,
                              void* d_out, int out_size, void* d_ws, size_t ws_size,
                              hipStream_t stream) {
    const float* h     = (const float*)d_in[0];
    const int*   ep    = (const int*)d_in[1];
    const float* gamma = (const float*)d_in[2];
    const float* beta  = (const float*)d_in[3];
    const float* W1    = (const float*)d_in[4];
    const float* b1    = (const float*)d_in[5];
    const float* W2    = (const float*)d_in[6];
    const float* b2    = (const float*)d_in[7];
    float* out = (float*)d_out;

    unsigned short* hb = (unsigned short*)d_ws;                      // 12,800,000 B
    unsigned short* Wt = (unsigned short*)((char*)d_ws + 12800000);  // 16,384 B
    float* GB = (float*)((char*)d_ws + 12800000 + 16384);            // 64 floats

    prep_kernel<<<CONV_BLOCKS + 32, 256, 0, stream>>>(h, hb, gamma, beta, W1, Wt, GB);
    edgehead_kernel<<<2048, 256, 0, stream>>>(hb, ep, b1, W2, b2, Wt, GB, out);
}